// Round 3
// baseline (371.006 us; speedup 1.0000x reference)
//
#include <hip/hip_runtime.h>
#include <math.h>

// GatingNetwork R9: K-split TLP. R8 was pure-latency-bound: 1 wave/SIMD
// (Occ 10.4%), MfmaUtil 10.6% (= the 10us MFMA floor diluted 9x), VALU 16%,
// and VGPR_Count=104 proves the compiler collapsed the planned 144-reg
// prefetch pipeline (sank loads to uses) -> every kstep pays full L2/L3
// latency with zero TLP to absorb it.
//
// R9: block = 256 thr (4 waves), each block owns 16 tokens; wave w computes
// the SAME 16 tokens x 64 experts over K-quarter [w*512,(w+1)*512) =
// 16 ksteps, then LDS reduction partial[4][16][65] (+bias) merges fp32
// partials. Grid 1024 blocks -> 4096 waves = 4 waves/SIMD, all co-resident
// (104 VGPR <= 128 budget @ __launch_bounds__(256,4)). No redundant loads:
// waves read disjoint x columns + disjoint B ksteps; split3 work also
// divided 4-way. TLP hides latency regardless of compiler scheduling.
//
//  * wconv_kernel (unchanged): RNE 3-way bf16 split of W into d_ws as
//    MFMA-B-fragment planes. frag(ks,nt,p) at ((ks*12+nt*3+p)*512+l*8)
//    shorts; lane l elem j = W[ks*32+(l>>4)*8+j][nt*16+(l&15)].
//    ws_size >= 786432 B required.
//  * Numerics: same 6-term RNE split MFMA sequence as R8 (passed,
//    absmax 9.8e-4); only change is fp32 partial-sum association (~1e-7).
//  * Epilogue: sum pass (256 thr, conflict-free), wave0 does 4-lanes-per-
//    row softmax/top-2 (strict >, tie->lower index = jax top_k), then
//    coalesced weights write by all 256 threads.
//
// Predictions: main dispatch 93 -> 22-30us; Occupancy ~40-50%; MfmaUtil
// 35-45%; VALUBusy 40-55%; FETCH ~68MB unchanged; bank conflicts <200K.
// If >45us with MfmaUtil <25%: latency still exposed -> LDS-stage B next.

#define T_TOK 16384
#define DMOD  2048
#define NEXP  64
#define NKSW  16   // ksteps per wave (512 of K per wave)

typedef __attribute__((ext_vector_type(8))) short short8;
typedef __attribute__((ext_vector_type(4))) float f32x4;

#define MFMA16 __builtin_amdgcn_mfma_f32_16x16x32_bf16

__device__ __forceinline__ unsigned short bf16_rne(float f) {
  unsigned int u = __float_as_uint(f);
  unsigned int r = (u + 0x7fffu + ((u >> 16) & 1u)) >> 16;
  return (unsigned short)r;
}
__device__ __forceinline__ float bf16_up(unsigned short h) {
  return __uint_as_float(((unsigned int)h) << 16);
}

// RNE 3-way bf16 split of a pair, packed little-endian (elem0 -> low 16).
// Residuals bounded 2^-8 per level; dropped cross terms ~2^-27 (R6-proven).
__device__ __forceinline__ void split3_pair(float v0, float v1, unsigned& hp,
                                            unsigned& mp, unsigned& lp) {
  const unsigned short h0 = bf16_rne(v0), h1 = bf16_rne(v1);
  const float e0 = v0 - bf16_up(h0), e1 = v1 - bf16_up(h1);
  const unsigned short m0 = bf16_rne(e0), m1 = bf16_rne(e1);
  const float g0 = e0 - bf16_up(m0), g1 = e1 - bf16_up(m1);
  const unsigned short l0 = bf16_rne(g0), l1 = bf16_rne(g1);
  hp = (unsigned)h0 | ((unsigned)h1 << 16);
  mp = (unsigned)m0 | ((unsigned)m1 << 16);
  lp = (unsigned)l0 | ((unsigned)l1 << 16);
}

__global__ __launch_bounds__(256) void wconv_kernel(
    const float* __restrict__ W, unsigned short* __restrict__ wp) {
  const int tid = blockIdx.x * 256 + threadIdx.x;  // 0..16383
  const int l = tid & 63;
  const int g = tid >> 6;            // g = ks*4 + nt, 0..255
  const int q = l >> 4, c = l & 15;
  const int ks = g >> 2, nt = g & 3;
  const int k0 = ks * 32 + q * 8;
  const int n = nt * 16 + c;
  float v[8];
#pragma unroll
  for (int j = 0; j < 8; ++j) v[j] = W[(size_t)(k0 + j) * NEXP + n];
  uint4 h, m, lo;
  split3_pair(v[0], v[1], h.x, m.x, lo.x);
  split3_pair(v[2], v[3], h.y, m.y, lo.y);
  split3_pair(v[4], v[5], h.z, m.z, lo.z);
  split3_pair(v[6], v[7], h.w, m.w, lo.w);
  unsigned short* base = wp + (size_t)g * 1536 + l * 8;
  *(uint4*)(base) = h;
  *(uint4*)(base + 512) = m;
  *(uint4*)(base + 1024) = lo;
}

__global__ __launch_bounds__(256, 4) void gating_kernel(
    const float* __restrict__ x, const unsigned short* __restrict__ wp,
    const float* __restrict__ bias, float* __restrict__ out) {
  __shared__ float partial[4 * 16 * 65];  // [wave][token][expert(+pad)]
  __shared__ float red_m[16];
  __shared__ float red_s[16];
  float* lg = partial;  // summed logits live in wave-0 plane after sum pass

  const int tid = threadIdx.x;
  const int l = tid & 63;   // lane
  const int w = tid >> 6;   // wave = K-quarter
  const int q = l >> 4, c = l & 15;
  const int t0 = blockIdx.x * 16;

  // wave w covers global ksteps [w*16, w*16+16)
  const float* xg = x + (size_t)(t0 + c) * DMOD + w * 512 + q * 8;
  const unsigned short* wl = wp + (size_t)(w * NKSW) * 6144 + l * 8;

  f32x4 acc[4];
#pragma unroll
  for (int nt = 0; nt < 4; ++nt) acc[nt] = (f32x4){0.f, 0.f, 0.f, 0.f};

  float4 xr[4][2];   // raw x for local kstep == i (mod 4); distance 4
  short8 bb[2][12];  // B frags, double-buffered (distance 2)

  // prologue
#pragma unroll
  for (int i = 0; i < 4; ++i) {
    xr[i][0] = *(const float4*)(xg + i * 32);
    xr[i][1] = *(const float4*)(xg + i * 32 + 4);
  }
#pragma unroll
  for (int i = 0; i < 12; ++i) {
    bb[0][i] = *(const short8*)(wl + (size_t)i * 512);
    bb[1][i] = *(const short8*)(wl + (size_t)(12 + i) * 512);
  }

  for (int blk = 0; blk < 4; ++blk) {
#pragma unroll
    for (int u = 0; u < 4; ++u) {
      const int ks = blk * 4 + u;  // local kstep 0..15
      // convert current x (registers only)
      short8 ah, am, al;
      {
        uint4 h, m, lo;
        split3_pair(xr[u][0].x, xr[u][0].y, h.x, m.x, lo.x);
        split3_pair(xr[u][0].z, xr[u][0].w, h.y, m.y, lo.y);
        split3_pair(xr[u][1].x, xr[u][1].y, h.z, m.z, lo.z);
        split3_pair(xr[u][1].z, xr[u][1].w, h.w, m.w, lo.w);
        ah = *(short8*)&h;
        am = *(short8*)&m;
        al = *(short8*)&lo;
      }
      // refill this x slot for ks+4 (clamped tail reads harmless)
      {
        const int kn = (ks + 4 < NKSW) ? ks + 4 : NKSW - 1;
        xr[u][0] = *(const float4*)(xg + kn * 32);
        xr[u][1] = *(const float4*)(xg + kn * 32 + 4);
      }
      // 6 exact-split terms x 4 n-tiles
      const int pb = u & 1;
#pragma unroll
      for (int nt = 0; nt < 4; ++nt) {
        const short8 bh = bb[pb][nt * 3 + 0];
        const short8 bm = bb[pb][nt * 3 + 1];
        const short8 bl = bb[pb][nt * 3 + 2];
        acc[nt] = MFMA16(ah, bh, acc[nt], 0, 0, 0);
        acc[nt] = MFMA16(ah, bm, acc[nt], 0, 0, 0);
        acc[nt] = MFMA16(am, bh, acc[nt], 0, 0, 0);
        acc[nt] = MFMA16(am, bm, acc[nt], 0, 0, 0);
        acc[nt] = MFMA16(ah, bl, acc[nt], 0, 0, 0);
        acc[nt] = MFMA16(al, bh, acc[nt], 0, 0, 0);
      }
      // refill this B buffer for ks+2
      {
        const int kn = (ks + 2 < NKSW) ? ks + 2 : NKSW - 1;
        const unsigned short* src = wl + (size_t)kn * 6144;
#pragma unroll
        for (int i = 0; i < 12; ++i)
          bb[pb][i] = *(const short8*)(src + (size_t)i * 512);
      }
    }
  }

  // ---- wave partials -> LDS (D: col=c -> expert nt*16+c, row=q*4+r) ----
#pragma unroll
  for (int nt = 0; nt < 4; ++nt)
#pragma unroll
    for (int r = 0; r < 4; ++r)
      partial[w * 1040 + (q * 4 + r) * 65 + nt * 16 + c] = acc[nt][r];
  __syncthreads();

  // ---- sum pass: lg[t][e] = sum_w partial[w][t][e] + bias[e] ----
  // 256 threads x 4 entries, lanes consecutive in e -> conflict-free.
#pragma unroll
  for (int r2 = 0; r2 < 4; ++r2) {
    const int idx = r2 * 256 + tid;      // 0..1023
    const int tt = idx >> 6;
    const int e = idx & 63;
    const int o = tt * 65 + e;
    const float s =
        partial[o] + partial[1040 + o] + partial[2080 + o] + partial[3120 + o];
    lg[o] = s + bias[e];
  }
  __syncthreads();

  // ---- wave 0: softmax stats + top-2, 4 lanes per token row ----
  if (tid < 64) {
    const int row = l >> 2;  // 0..15
    const int s = l & 3;     // expert slice s*16..s*16+15
    const float* lr = lg + row * 65 + s * 16;
    float mx = -INFINITY;
#pragma unroll
    for (int e = 0; e < 16; ++e) mx = fmaxf(mx, lr[e]);
    mx = fmaxf(mx, __shfl_xor(mx, 1));
    mx = fmaxf(mx, __shfl_xor(mx, 2));
    float sum = 0.f, b1 = -INFINITY, b2 = -INFINITY;
    int i1 = 0, i2 = 0;
#pragma unroll
    for (int e = 0; e < 16; ++e) {
      const float v = lr[e];
      sum += expf(v - mx);
      const int idx = s * 16 + e;
      if (v > b1) {  // strict >: ties keep lowest index (jax top_k)
        b2 = b1; i2 = i1; b1 = v; i1 = idx;
      } else if (v > b2) {
        b2 = v; i2 = idx;
      }
    }
#pragma unroll
    for (int msk = 1; msk <= 2; msk <<= 1) {
      sum += __shfl_xor(sum, msk);
      const float ob1 = __shfl_xor(b1, msk);
      const int oi1 = __shfl_xor(i1, msk);
      const float ob2 = __shfl_xor(b2, msk);
      const int oi2 = __shfl_xor(i2, msk);
      float n1, n2;
      int j1, j2;
      const bool aFirst = (b1 > ob1) || (b1 == ob1 && i1 < oi1);
      if (aFirst) {
        n1 = b1; j1 = i1;
        const bool t = (b2 > ob1) || (b2 == ob1 && i2 < oi1);
        n2 = t ? b2 : ob1; j2 = t ? i2 : oi1;
      } else {
        n1 = ob1; j1 = oi1;
        const bool t = (ob2 > b1) || (ob2 == b1 && oi2 < i1);
        n2 = t ? ob2 : b1; j2 = t ? oi2 : i1;
      }
      b1 = n1; i1 = j1; b2 = n2; i2 = j2;
    }
    if (s == 0) {
      const float inv = 1.f / sum;
      const int t = t0 + row;
      float2 wv, iv;
      wv.x = expf(b1 - mx) * inv;
      wv.y = expf(b2 - mx) * inv;
      iv.x = (float)i1;
      iv.y = (float)i2;
      *(float2*)(out + 2 * t) = wv;
      *(float2*)(out + 2 * T_TOK + 2 * t) = iv;
      red_m[row] = mx;
      red_s[row] = inv;
    }
  }
  __syncthreads();

  // ---- full softmax weights, coalesced: 256 thr x 4 entries ----
#pragma unroll
  for (int r2 = 0; r2 < 4; ++r2) {
    const int idx = r2 * 256 + tid;
    const int tt = idx >> 6;
    const int e = idx & 63;
    out[4 * T_TOK + (size_t)(t0 + tt) * NEXP + e] =
        expf(lg[tt * 65 + e] - red_m[tt]) * red_s[tt];
  }
}

extern "C" void kernel_launch(void* const* d_in, const int* in_sizes, int n_in,
                              void* d_out, int out_size, void* d_ws,
                              size_t ws_size, hipStream_t stream) {
  const float* x = (const float*)d_in[0];
  const float* W = (const float*)d_in[1];
  const float* b = (const float*)d_in[2];
  float* out = (float*)d_out;
  unsigned short* wp = (unsigned short*)d_ws;  // needs 786432 B
  wconv_kernel<<<dim3(64), dim3(256), 0, stream>>>(W, wp);
  gating_kernel<<<dim3(T_TOK / 16), dim3(256), 0, stream>>>(x, wp, b, out);
}

// Round 4
// 219.768 us; speedup vs baseline: 1.6882x; 1.6882x over previous
//
#include <hip/hip_runtime.h>
#include <math.h>

// GatingNetwork R10: R9's K-split TLP with a register budget that fits.
//   logits = x[16384,2048] @ W[2048,64] + b; softmax; top-2.
//   Out (fp32 flat): topk_w[T,2] | topk_idx[T,2] (float) | weights[T,E].
//
// R9 post-mortem: __launch_bounds__(256,4) capped regs at 128/wave while the
// pipeline needed ~160 -> allocator kept 64 VGPR and spilled the B double-
// buffer to scratch: WRITE_SIZE 4.4->395 MB, FETCH 69->261 MB, 236us. The
// K-split itself was right (Occ 42%, numerics passed).
//
// R10: same structure, slim pipeline (~100 VGPR -> 4 waves/SIMD naturally):
//  * __launch_bounds__(256) only — no min-waves constraint.
//  * B SINGLE-buffered bb[12] (48 regs), refilled for ks+1 after the MFMAs;
//    next kstep's ~200cy of x-convert VALU + 4-wave TLP hides the L1/L2 hit.
//  * x prefetch distance 2 in four NAMED float4 (16 regs, static indexing).
//  * wconv_kernel / fragment layout / 6-term RNE split MFMA sequence /
//    LDS reduction / epilogue: identical to R9 (numerically validated).
//    ws_size >= 786432 B required.
//
// Predictions: passes (~9.8e-4); main dispatch 20-35us; WRITE_SIZE back to
// ~4.4MB, FETCH 70-140MB (spill gone = headline check); VGPR ~100-110;
// Occ 40-50%; MfmaUtil 25-45%; VALUBusy 35-60%. If >60us with utils low and
// no spill traffic: latency still exposed -> global_load_lds shared-B next.

#define T_TOK 16384
#define DMOD  2048
#define NEXP  64
#define NKSW  16   // ksteps per wave (512 of K per wave)

typedef __attribute__((ext_vector_type(8))) short short8;
typedef __attribute__((ext_vector_type(4))) float f32x4;

#define MFMA16 __builtin_amdgcn_mfma_f32_16x16x32_bf16

__device__ __forceinline__ unsigned short bf16_rne(float f) {
  unsigned int u = __float_as_uint(f);
  unsigned int r = (u + 0x7fffu + ((u >> 16) & 1u)) >> 16;
  return (unsigned short)r;
}
__device__ __forceinline__ float bf16_up(unsigned short h) {
  return __uint_as_float(((unsigned int)h) << 16);
}

// RNE 3-way bf16 split of a pair, packed little-endian (elem0 -> low 16).
// Residuals bounded 2^-8 per level; dropped cross terms ~2^-27 (R6-proven).
__device__ __forceinline__ void split3_pair(float v0, float v1, unsigned& hp,
                                            unsigned& mp, unsigned& lp) {
  const unsigned short h0 = bf16_rne(v0), h1 = bf16_rne(v1);
  const float e0 = v0 - bf16_up(h0), e1 = v1 - bf16_up(h1);
  const unsigned short m0 = bf16_rne(e0), m1 = bf16_rne(e1);
  const float g0 = e0 - bf16_up(m0), g1 = e1 - bf16_up(m1);
  const unsigned short l0 = bf16_rne(g0), l1 = bf16_rne(g1);
  hp = (unsigned)h0 | ((unsigned)h1 << 16);
  mp = (unsigned)m0 | ((unsigned)m1 << 16);
  lp = (unsigned)l0 | ((unsigned)l1 << 16);
}

__global__ __launch_bounds__(256) void wconv_kernel(
    const float* __restrict__ W, unsigned short* __restrict__ wp) {
  const int tid = blockIdx.x * 256 + threadIdx.x;  // 0..16383
  const int l = tid & 63;
  const int g = tid >> 6;            // g = ks*4 + nt, 0..255
  const int q = l >> 4, c = l & 15;
  const int ks = g >> 2, nt = g & 3;
  const int k0 = ks * 32 + q * 8;
  const int n = nt * 16 + c;
  float v[8];
#pragma unroll
  for (int j = 0; j < 8; ++j) v[j] = W[(size_t)(k0 + j) * NEXP + n];
  uint4 h, m, lo;
  split3_pair(v[0], v[1], h.x, m.x, lo.x);
  split3_pair(v[2], v[3], h.y, m.y, lo.y);
  split3_pair(v[4], v[5], h.z, m.z, lo.z);
  split3_pair(v[6], v[7], h.w, m.w, lo.w);
  unsigned short* base = wp + (size_t)g * 1536 + l * 8;
  *(uint4*)(base) = h;
  *(uint4*)(base + 512) = m;
  *(uint4*)(base + 1024) = lo;
}

// One kstep: convert x slot, refill it for KS+2, 24 MFMA, refill bb for KS+1.
#define KSTEP_BODY(KS, XA, XB)                                           \
  {                                                                      \
    short8 ah, am, al;                                                   \
    {                                                                    \
      uint4 h, m, lo;                                                    \
      split3_pair(XA.x, XA.y, h.x, m.x, lo.x);                           \
      split3_pair(XA.z, XA.w, h.y, m.y, lo.y);                           \
      split3_pair(XB.x, XB.y, h.z, m.z, lo.z);                           \
      split3_pair(XB.z, XB.w, h.w, m.w, lo.w);                           \
      ah = *(short8*)&h;                                                 \
      am = *(short8*)&m;                                                 \
      al = *(short8*)&lo;                                                \
    }                                                                    \
    {                                                                    \
      const int kn = ((KS) + 2 < NKSW) ? (KS) + 2 : NKSW - 1;            \
      XA = *(const float4*)(xg + kn * 32);                               \
      XB = *(const float4*)(xg + kn * 32 + 4);                           \
    }                                                                    \
    _Pragma("unroll") for (int nt = 0; nt < 4; ++nt) {                   \
      const short8 bh = bb[nt * 3 + 0];                                  \
      const short8 bm = bb[nt * 3 + 1];                                  \
      const short8 bl = bb[nt * 3 + 2];                                  \
      acc[nt] = MFMA16(ah, bh, acc[nt], 0, 0, 0);                        \
      acc[nt] = MFMA16(ah, bm, acc[nt], 0, 0, 0);                        \
      acc[nt] = MFMA16(am, bh, acc[nt], 0, 0, 0);                        \
      acc[nt] = MFMA16(am, bm, acc[nt], 0, 0, 0);                        \
      acc[nt] = MFMA16(ah, bl, acc[nt], 0, 0, 0);                        \
      acc[nt] = MFMA16(al, bh, acc[nt], 0, 0, 0);                        \
    }                                                                    \
    {                                                                    \
      const int kn = ((KS) + 1 < NKSW) ? (KS) + 1 : NKSW - 1;            \
      const unsigned short* src = wl + (size_t)kn * 6144;                \
      _Pragma("unroll") for (int i = 0; i < 12; ++i)                     \
          bb[i] = *(const short8*)(src + (size_t)i * 512);               \
    }                                                                    \
  }

__global__ __launch_bounds__(256) void gating_kernel(
    const float* __restrict__ x, const unsigned short* __restrict__ wp,
    const float* __restrict__ bias, float* __restrict__ out) {
  __shared__ float partial[4 * 16 * 65];  // [wave][token][expert(+pad)]
  __shared__ float red_m[16];
  __shared__ float red_s[16];
  float* lg = partial;  // summed logits live in wave-0 plane after sum pass

  const int tid = threadIdx.x;
  const int l = tid & 63;   // lane
  const int w = tid >> 6;   // wave = K-quarter
  const int q = l >> 4, c = l & 15;
  const int t0 = blockIdx.x * 16;

  // wave w covers global ksteps [w*16, w*16+16)
  const float* xg = x + (size_t)(t0 + c) * DMOD + w * 512 + q * 8;
  const unsigned short* wl = wp + (size_t)(w * NKSW) * 6144 + l * 8;

  f32x4 acc[4];
#pragma unroll
  for (int nt = 0; nt < 4; ++nt) acc[nt] = (f32x4){0.f, 0.f, 0.f, 0.f};

  // x prefetch distance 2, NAMED slots (static indexing; rule #20).
  float4 xr0a = *(const float4*)(xg);
  float4 xr0b = *(const float4*)(xg + 4);
  float4 xr1a = *(const float4*)(xg + 32);
  float4 xr1b = *(const float4*)(xg + 36);

  // B single buffer: 12 frags (48 VGPR), kstep 0 resident.
  short8 bb[12];
#pragma unroll
  for (int i = 0; i < 12; ++i)
    bb[i] = *(const short8*)(wl + (size_t)i * 512);

  for (int blk = 0; blk < 8; ++blk) {
    const int ks0 = blk * 2;
    KSTEP_BODY(ks0, xr0a, xr0b)
    KSTEP_BODY(ks0 + 1, xr1a, xr1b)
  }

  // ---- wave partials -> LDS (D: col=c -> expert nt*16+c, row=q*4+r) ----
#pragma unroll
  for (int nt = 0; nt < 4; ++nt)
#pragma unroll
    for (int r = 0; r < 4; ++r)
      partial[w * 1040 + (q * 4 + r) * 65 + nt * 16 + c] = acc[nt][r];
  __syncthreads();

  // ---- sum pass: lg[t][e] = sum_w partial[w][t][e] + bias[e] ----
  // 256 threads x 4 entries, lanes consecutive in e -> conflict-free.
#pragma unroll
  for (int r2 = 0; r2 < 4; ++r2) {
    const int idx = r2 * 256 + tid;      // 0..1023
    const int tt = idx >> 6;
    const int e = idx & 63;
    const int o = tt * 65 + e;
    const float s =
        partial[o] + partial[1040 + o] + partial[2080 + o] + partial[3120 + o];
    lg[o] = s + bias[e];
  }
  __syncthreads();

  // ---- wave 0: softmax stats + top-2, 4 lanes per token row ----
  if (tid < 64) {
    const int row = l >> 2;  // 0..15
    const int s = l & 3;     // expert slice s*16..s*16+15
    const float* lr = lg + row * 65 + s * 16;
    float mx = -INFINITY;
#pragma unroll
    for (int e = 0; e < 16; ++e) mx = fmaxf(mx, lr[e]);
    mx = fmaxf(mx, __shfl_xor(mx, 1));
    mx = fmaxf(mx, __shfl_xor(mx, 2));
    float sum = 0.f, b1 = -INFINITY, b2 = -INFINITY;
    int i1 = 0, i2 = 0;
#pragma unroll
    for (int e = 0; e < 16; ++e) {
      const float v = lr[e];
      sum += expf(v - mx);
      const int idx = s * 16 + e;
      if (v > b1) {  // strict >: ties keep lowest index (jax top_k)
        b2 = b1; i2 = i1; b1 = v; i1 = idx;
      } else if (v > b2) {
        b2 = v; i2 = idx;
      }
    }
#pragma unroll
    for (int msk = 1; msk <= 2; msk <<= 1) {
      sum += __shfl_xor(sum, msk);
      const float ob1 = __shfl_xor(b1, msk);
      const int oi1 = __shfl_xor(i1, msk);
      const float ob2 = __shfl_xor(b2, msk);
      const int oi2 = __shfl_xor(i2, msk);
      float n1, n2;
      int j1, j2;
      const bool aFirst = (b1 > ob1) || (b1 == ob1 && i1 < oi1);
      if (aFirst) {
        n1 = b1; j1 = i1;
        const bool t = (b2 > ob1) || (b2 == ob1 && i2 < oi1);
        n2 = t ? b2 : ob1; j2 = t ? i2 : oi1;
      } else {
        n1 = ob1; j1 = oi1;
        const bool t = (ob2 > b1) || (ob2 == b1 && oi2 < i1);
        n2 = t ? ob2 : b1; j2 = t ? oi2 : i1;
      }
      b1 = n1; i1 = j1; b2 = n2; i2 = j2;
    }
    if (s == 0) {
      const float inv = 1.f / sum;
      const int t = t0 + row;
      float2 wv, iv;
      wv.x = expf(b1 - mx) * inv;
      wv.y = expf(b2 - mx) * inv;
      iv.x = (float)i1;
      iv.y = (float)i2;
      *(float2*)(out + 2 * t) = wv;
      *(float2*)(out + 2 * T_TOK + 2 * t) = iv;
      red_m[row] = mx;
      red_s[row] = inv;
    }
  }
  __syncthreads();

  // ---- full softmax weights, coalesced: 256 thr x 4 entries ----
#pragma unroll
  for (int r2 = 0; r2 < 4; ++r2) {
    const int idx = r2 * 256 + tid;
    const int tt = idx >> 6;
    const int e = idx & 63;
    out[4 * T_TOK + (size_t)(t0 + tt) * NEXP + e] =
        expf(lg[tt * 65 + e] - red_m[tt]) * red_s[tt];
  }
}

extern "C" void kernel_launch(void* const* d_in, const int* in_sizes, int n_in,
                              void* d_out, int out_size, void* d_ws,
                              size_t ws_size, hipStream_t stream) {
  const float* x = (const float*)d_in[0];
  const float* W = (const float*)d_in[1];
  const float* b = (const float*)d_in[2];
  float* out = (float*)d_out;
  unsigned short* wp = (unsigned short*)d_ws;  // needs 786432 B
  wconv_kernel<<<dim3(64), dim3(256), 0, stream>>>(W, wp);
  gating_kernel<<<dim3(T_TOK / 16), dim3(256), 0, stream>>>(x, wp, b, out);
}